// Round 1
// baseline (1196.973 us; speedup 1.0000x reference)
//
#include <hip/hip_runtime.h>

static constexpr int N  = 128;   // N_STATE
static constexpr int S  = 8192;  // SEQ
static constexpr int L  = 128;   // chunk length
static constexpr int NC = 64;    // S/L
static constexpr int OD = 1000;  // OUT_DIM
#define SCL 0.25f                // 1/sqrt(D_HEAD=16)

// ws layout (floats):
//  QT[0..128]: (GA^i)^T row-major, QT[i][m][n] = (GA^i)[n][m]   129*16384
//  g[k][n] = (GA^k GB)[n], k=0..127                              128*128
//  locsum[j][s][n]                                               64*3*128
//  bounds[j][s][n], j=0..64                                      65*3*128
//  cs[s][t][n]  (q,k,v HiPPO states)                             3*8192*128
//  ctx[t][n]                                                     8192*128

// ---- QT[1] = GA^T ----
__global__ void k_copyT(const float* __restrict__ GA, float* __restrict__ QT1){
  int idx = blockIdx.x*256 + threadIdx.x;   // 0..16383
  int m = idx >> 7, n = idx & 127;
  QT1[idx] = GA[n*N + m];
}

// ---- QT[mlev+i] = QT[mlev] @ QT[i], i=1..mlev (log-doubling of powers) ----
__global__ __launch_bounds__(256) void k_powmm(float* QT, int mlev){
  int i = blockIdx.z + 1;
  const float* Am = QT + (size_t)mlev*(N*N);
  const float* Ai = QT + (size_t)i*(N*N);
  float* C = QT + (size_t)(mlev+i)*(N*N);
  __shared__ __align__(16) float As[16][68];
  __shared__ __align__(16) float Bs[16][68];
  int bm = blockIdx.y, bn = blockIdx.x;
  int tx = threadIdx.x, ty = threadIdx.y;
  int tid = ty*16 + tx;
  float acc[4][4] = {};
  for (int kt = 0; kt < N; kt += 16){
    int row = tid >> 2, kc = (tid & 3) << 2;
    float4 av = *(const float4*)(Am + (size_t)(bm*64+row)*N + kt + kc);
    As[kc+0][row]=av.x; As[kc+1][row]=av.y; As[kc+2][row]=av.z; As[kc+3][row]=av.w;
    int bk = tid >> 4, c0 = (tid & 15) << 2;
    *(float4*)&Bs[bk][c0] = *(const float4*)(Ai + (size_t)(kt+bk)*N + bn*64 + c0);
    __syncthreads();
#pragma unroll
    for (int kk = 0; kk < 16; ++kk){
      float4 a = *(const float4*)&As[kk][ty*4];
      float4 b = *(const float4*)&Bs[kk][tx*4];
      float aa[4]={a.x,a.y,a.z,a.w}, bb[4]={b.x,b.y,b.z,b.w};
#pragma unroll
      for (int ii=0; ii<4; ++ii)
#pragma unroll
        for (int jj=0; jj<4; ++jj) acc[ii][jj] += aa[ii]*bb[jj];
    }
    __syncthreads();
  }
#pragma unroll
  for (int ii=0; ii<4; ++ii){
    float4 vst = make_float4(acc[ii][0],acc[ii][1],acc[ii][2],acc[ii][3]);
    *(float4*)(C + (size_t)(bm*64+ty*4+ii)*N + bn*64 + tx*4) = vst;
  }
}

// ---- g[k] = GA^k GB  (QT stored transposed -> coalesced over n) ----
__global__ void k_g(const float* __restrict__ QT, const float* __restrict__ GB,
                    float* __restrict__ g){
  int kb = blockIdx.x;   // 0..127
  int n = threadIdx.x;   // 128
  if (kb == 0){ g[n] = GB[n]; return; }
  const float* Qk = QT + (size_t)kb*(N*N);
  float acc = 0.0f;
  for (int m = 0; m < N; ++m) acc += Qk[m*N + n]*GB[m];
  g[kb*N + n] = acc;
}

// ---- locsum[j][s] = sum_{k} f[jL+L-1-k] * g[k]  (local part of chunk-end state) ----
__global__ void k_locsum(const float* __restrict__ fq, const float* __restrict__ fk,
                         const float* __restrict__ fv, const float* __restrict__ g,
                         float* __restrict__ locsum){
  int j = blockIdx.x, s = blockIdx.y;
  const float* f = (s==0)? fq : (s==1)? fk : fv;
  __shared__ float fr[L];
  int n = threadIdx.x;   // 128
  fr[n] = f[j*L + (L-1) - n];
  __syncthreads();
  float acc = 0.0f;
  for (int kk = 0; kk < L; ++kk) acc += fr[kk]*g[kk*N + n];
  locsum[(j*3+s)*N + n] = acc;
}

// ---- sequential chunk-boundary scan: b_{j+1} = GA^L b_j + locsum[j] ----
__global__ void k_bscan(const float* __restrict__ QT, const float* __restrict__ locsum,
                        float* __restrict__ bounds){
  __shared__ float bc[3][N];
  __shared__ float bnx[3][N];
  int tid = threadIdx.x;          // 384
  int s = tid >> 7, n = tid & 127;
  const float* QL = QT + (size_t)L*(N*N);  // (GA^L)^T
  bc[s][n] = 0.0f;
  bounds[(0*3+s)*N + n] = 0.0f;
  __syncthreads();
  for (int j = 0; j < NC; ++j){
    float acc = locsum[(j*3+s)*N + n];
    for (int m = 0; m < N; ++m) acc += QL[m*N+n]*bc[s][m];
    bnx[s][n] = acc;
    bounds[((j+1)*3+s)*N + n] = acc;
    __syncthreads();
    bc[s][n] = bnx[s][n];
    __syncthreads();
  }
}

// ---- within-chunk causal conv: cs[s][jL+i] = sum_{k<=i} f[jL+i-k]*g[k] ----
__global__ void k_fill_local(const float* __restrict__ fq, const float* __restrict__ fk,
                             const float* __restrict__ fv, const float* __restrict__ g,
                             float* __restrict__ cs){
  int j = blockIdx.x, s = blockIdx.y, h = blockIdx.z;  // h: n-half
  const float* f = (s==0)? fq : (s==1)? fk : fv;
  __shared__ float gs[L][64];
  __shared__ float fl[L];
  int t = threadIdx.x;  // 64
  for (int kk = 0; kk < L; ++kk) gs[kk][t] = g[kk*N + h*64 + t];
  fl[t]    = f[j*L + t];
  fl[64+t] = f[j*L + 64 + t];
  __syncthreads();
  float* outp = cs + ((size_t)s*S + (size_t)j*L)*N + h*64 + t;
  for (int i = 0; i < L; ++i){
    float acc = 0.0f;
    for (int kk = 0; kk <= i; ++kk) acc += fl[i-kk]*gs[kk][t];
    outp[(size_t)i*N] = acc;
  }
}

// ---- boundary fill: cs[s][jL+i] += GA^{i+1} b_j ----
__global__ __launch_bounds__(128) void k_fill_bound(const float* __restrict__ QT,
                          const float* __restrict__ bounds, float* __restrict__ cs){
  int i = blockIdx.x;     // 0..L-1
  int jg = blockIdx.y;    // 0..3
  __shared__ float Qs[N*N];   // 64 KB, Qs[m*N+n] = (GA^{i+1})[n][m]
  int n = threadIdx.x;    // 128
  const float* Qg = QT + (size_t)(i+1)*(N*N);
  for (int idx = n; idx < N*N; idx += 128) Qs[idx] = Qg[idx];
  __syncthreads();
  for (int jj = 0; jj < NC/4; ++jj){
    int j = jg*(NC/4) + jj;
    for (int s = 0; s < 3; ++s){
      const float* b = bounds + (j*3+s)*N;
      float acc = 0.0f;
      for (int m = 0; m < N; ++m) acc += Qs[m*N+n]*b[m];
      cs[((size_t)s*S + (size_t)j*L + i)*N + n] += acc;
    }
  }
}

// ---- raw scores: attn[t][u] = 0.25 * qs[t].ks[u]   (A@B^T, 128x128 tiles) ----
__global__ __launch_bounds__(256) void k_score(const float* __restrict__ cs,
                                               float* __restrict__ attn){
  const float* A = cs;                 // q states
  const float* B = cs + (size_t)S*N;   // k states
  __shared__ __align__(16) float As[16][132];
  __shared__ __align__(16) float Bs[16][132];
  int bm = blockIdx.y, bn = blockIdx.x;
  int tx = threadIdx.x, ty = threadIdx.y;
  int tid = ty*16 + tx;
  float acc[8][8] = {};
  for (int kt = 0; kt < N; kt += 16){
#pragma unroll
    for (int ld = 0; ld < 2; ++ld){
      int idx = tid + ld*256;
      int r2 = idx >> 2, k2 = (idx & 3) << 2;
      float4 av = *(const float4*)(A + (size_t)(bm*128+r2)*N + kt + k2);
      As[k2+0][r2]=av.x; As[k2+1][r2]=av.y; As[k2+2][r2]=av.z; As[k2+3][r2]=av.w;
      float4 bv = *(const float4*)(B + (size_t)(bn*128+r2)*N + kt + k2);
      Bs[k2+0][r2]=bv.x; Bs[k2+1][r2]=bv.y; Bs[k2+2][r2]=bv.z; Bs[k2+3][r2]=bv.w;
    }
    __syncthreads();
#pragma unroll
    for (int kk = 0; kk < 16; ++kk){
      float4 a0 = *(const float4*)&As[kk][ty*8];
      float4 a1 = *(const float4*)&As[kk][ty*8+4];
      float4 b0 = *(const float4*)&Bs[kk][tx*4];
      float4 b1 = *(const float4*)&Bs[kk][64+tx*4];
      float aa[8]={a0.x,a0.y,a0.z,a0.w,a1.x,a1.y,a1.z,a1.w};
      float bb[8]={b0.x,b0.y,b0.z,b0.w,b1.x,b1.y,b1.z,b1.w};
#pragma unroll
      for (int ii=0; ii<8; ++ii)
#pragma unroll
        for (int jj=0; jj<8; ++jj) acc[ii][jj] += aa[ii]*bb[jj];
    }
    __syncthreads();
  }
#pragma unroll
  for (int ii=0; ii<8; ++ii){
    size_t r = (size_t)(bm*128 + ty*8 + ii)*S + (size_t)bn*128;
    float4 v0 = make_float4(acc[ii][0]*SCL, acc[ii][1]*SCL, acc[ii][2]*SCL, acc[ii][3]*SCL);
    float4 v1 = make_float4(acc[ii][4]*SCL, acc[ii][5]*SCL, acc[ii][6]*SCL, acc[ii][7]*SCL);
    *(float4*)(attn + r + tx*4)      = v0;
    *(float4*)(attn + r + 64 + tx*4) = v1;
  }
}

// ---- exact row softmax in place (row staged in LDS) ----
__global__ __launch_bounds__(256) void k_softmax(float* __restrict__ attn){
  __shared__ __align__(16) float rowb[S];  // 32 KB
  __shared__ float red[256];
  int t = blockIdx.x;
  int tid = threadIdx.x;
  float4* g4 = (float4*)(attn + (size_t)t*S);
  float4* r4 = (float4*)rowb;
  float mx = -3.0e38f;
  for (int u = tid; u < S/4; u += 256){
    float4 v = g4[u];
    r4[u] = v;
    mx = fmaxf(mx, fmaxf(fmaxf(v.x,v.y), fmaxf(v.z,v.w)));
  }
  red[tid] = mx; __syncthreads();
  for (int st = 128; st > 0; st >>= 1){
    if (tid < st) red[tid] = fmaxf(red[tid], red[tid+st]);
    __syncthreads();
  }
  mx = red[0];
  __syncthreads();
  float sum = 0.0f;
  for (int u = tid; u < S/4; u += 256){
    float4 v = r4[u];
    v.x = __expf(v.x - mx); v.y = __expf(v.y - mx);
    v.z = __expf(v.z - mx); v.w = __expf(v.w - mx);
    r4[u] = v;
    sum += v.x + v.y + v.z + v.w;
  }
  red[tid] = sum; __syncthreads();
  for (int st = 128; st > 0; st >>= 1){
    if (tid < st) red[tid] += red[tid+st];
    __syncthreads();
  }
  float inv = 1.0f / red[0];
  for (int u = tid; u < S/4; u += 256){
    float4 v = r4[u];
    v.x *= inv; v.y *= inv; v.z *= inv; v.w *= inv;
    g4[u] = v;
  }
}

// ---- ctx = attn @ vs   (split-K=8, fp32 atomics into zeroed ctx) ----
__global__ __launch_bounds__(256) void k_context(const float* __restrict__ attn,
                       const float* __restrict__ vs, float* __restrict__ ctx){
  __shared__ __align__(16) float As[16][132];
  __shared__ __align__(16) float Bs[16][132];
  int kz = blockIdx.x;   // 0..7
  int bm = blockIdx.y;   // 0..63
  int tx = threadIdx.x, ty = threadIdx.y;
  int tid = ty*16 + tx;
  int k0 = kz*1024;
  float acc[8][8] = {};
  for (int kt = 0; kt < 1024; kt += 16){
#pragma unroll
    for (int ld = 0; ld < 2; ++ld){
      int idx = tid + ld*256;
      int r2 = idx >> 2, k2 = (idx & 3) << 2;
      float4 av = *(const float4*)(attn + (size_t)(bm*128+r2)*S + k0 + kt + k2);
      As[k2+0][r2]=av.x; As[k2+1][r2]=av.y; As[k2+2][r2]=av.z; As[k2+3][r2]=av.w;
      int bk = idx >> 5, c0 = (idx & 31) << 2;
      *(float4*)&Bs[bk][c0] = *(const float4*)(vs + (size_t)(k0+kt+bk)*N + c0);
    }
    __syncthreads();
#pragma unroll
    for (int kk = 0; kk < 16; ++kk){
      float4 a0 = *(const float4*)&As[kk][ty*8];
      float4 a1 = *(const float4*)&As[kk][ty*8+4];
      float4 b0 = *(const float4*)&Bs[kk][tx*4];
      float4 b1 = *(const float4*)&Bs[kk][64+tx*4];
      float aa[8]={a0.x,a0.y,a0.z,a0.w,a1.x,a1.y,a1.z,a1.w};
      float bb[8]={b0.x,b0.y,b0.z,b0.w,b1.x,b1.y,b1.z,b1.w};
#pragma unroll
      for (int ii=0; ii<8; ++ii)
#pragma unroll
        for (int jj=0; jj<8; ++jj) acc[ii][jj] += aa[ii]*bb[jj];
    }
    __syncthreads();
  }
#pragma unroll
  for (int ii=0; ii<8; ++ii){
    int r = bm*128 + ty*8 + ii;
#pragma unroll
    for (int jj=0; jj<4; ++jj){
      atomicAdd(&ctx[(size_t)r*N + tx*4 + jj],      acc[ii][jj]);
      atomicAdd(&ctx[(size_t)r*N + 64 + tx*4 + jj], acc[ii][4+jj]);
    }
  }
}

// ---- out = ctx @ Wp + bp ----
__global__ __launch_bounds__(256) void k_out(const float* __restrict__ ctx,
                   const float* __restrict__ Wp, const float* __restrict__ bp,
                   float* __restrict__ out){
  __shared__ __align__(16) float As[16][68];
  __shared__ __align__(16) float Bs[16][68];
  int bn = blockIdx.x;   // 0..15
  int bm = blockIdx.y;   // 0..127
  int tx = threadIdx.x, ty = threadIdx.y;
  int tid = ty*16 + tx;
  float acc[4][4] = {};
  for (int kt = 0; kt < N; kt += 16){
    int row = tid >> 2, kc = (tid & 3) << 2;
    float4 av = *(const float4*)(ctx + (size_t)(bm*64+row)*N + kt + kc);
    As[kc+0][row]=av.x; As[kc+1][row]=av.y; As[kc+2][row]=av.z; As[kc+3][row]=av.w;
    int bk = tid >> 4, c0 = (tid & 15) << 2;
#pragma unroll
    for (int jj = 0; jj < 4; ++jj){
      int c = bn*64 + c0 + jj;
      Bs[bk][c0+jj] = (c < OD) ? Wp[(size_t)(kt+bk)*OD + c] : 0.0f;
    }
    __syncthreads();
#pragma unroll
    for (int kk = 0; kk < 16; ++kk){
      float4 a = *(const float4*)&As[kk][ty*4];
      float4 b = *(const float4*)&Bs[kk][tx*4];
      float aa[4]={a.x,a.y,a.z,a.w}, bb[4]={b.x,b.y,b.z,b.w};
#pragma unroll
      for (int ii=0; ii<4; ++ii)
#pragma unroll
        for (int jj=0; jj<4; ++jj) acc[ii][jj] += aa[ii]*bb[jj];
    }
    __syncthreads();
  }
#pragma unroll
  for (int ii=0; ii<4; ++ii){
    int r = bm*64 + ty*4 + ii;
#pragma unroll
    for (int jj=0; jj<4; ++jj){
      int c = bn*64 + tx*4 + jj;
      if (c < OD) out[(size_t)r*OD + c] = acc[ii][jj] + bp[c];
    }
  }
}

extern "C" void kernel_launch(void* const* d_in, const int* in_sizes, int n_in,
                              void* d_out, int out_size, void* d_ws, size_t ws_size,
                              hipStream_t stream){
  const float* fq = (const float*)d_in[0];
  const float* fk = (const float*)d_in[1];
  const float* fv = (const float*)d_in[2];
  const float* GA = (const float*)d_in[3];
  const float* GB = (const float*)d_in[4];
  const float* Wp = (const float*)d_in[5];
  const float* bp = (const float*)d_in[6];
  float* out  = (float*)d_out;
  float* attn = out + (size_t)S*OD;

  float* ws     = (float*)d_ws;
  float* QT     = ws;                                // 129*16384
  float* g      = QT + (size_t)129*N*N;              // 128*128
  float* locsum = g + (size_t)L*N;                   // 64*3*128
  float* bounds = locsum + (size_t)NC*3*N;           // 65*3*128
  float* cs     = bounds + (size_t)(NC+1)*3*N;       // 3*8192*128
  float* ctx    = cs + (size_t)3*S*N;                // 8192*128
  // total ~25.5 MB of ws

  hipMemsetAsync(ctx, 0, (size_t)S*N*sizeof(float), stream);

  k_copyT<<<64, 256, 0, stream>>>(GA, QT + (size_t)N*N);
  for (int m = 1; m < L; m <<= 1)
    k_powmm<<<dim3(2,2,m), dim3(16,16), 0, stream>>>(QT, m);
  k_g<<<128, 128, 0, stream>>>(QT, GB, g);
  k_locsum<<<dim3(NC,3), 128, 0, stream>>>(fq, fk, fv, g, locsum);
  k_bscan<<<1, 384, 0, stream>>>(QT, locsum, bounds);
  k_fill_local<<<dim3(NC,3,2), 64, 0, stream>>>(fq, fk, fv, g, cs);
  k_fill_bound<<<dim3(L,4), 128, 0, stream>>>(QT, bounds, cs);
  k_score<<<dim3(S/128, S/128), dim3(16,16), 0, stream>>>(cs, attn);
  k_softmax<<<S, 256, 0, stream>>>(attn);
  k_context<<<dim3(8, S/128), dim3(16,16), 0, stream>>>(attn, cs + (size_t)2*S*N, ctx);
  k_out<<<dim3(16, S/64), dim3(16,16), 0, stream>>>(ctx, Wp, bp, out);
}

// Round 2
// 1038.201 us; speedup vs baseline: 1.1529x; 1.1529x over previous
//
#include <hip/hip_runtime.h>

static constexpr int N  = 128;   // N_STATE
static constexpr int S  = 8192;  // SEQ
static constexpr int L  = 128;   // chunk length
static constexpr int NC = 64;    // S/L
static constexpr int OD = 1000;  // OUT_DIM
static constexpr int KSPLIT = 16;
#define SCL 0.25f                // 1/sqrt(D_HEAD=16)

// ws layout (floats):
//  QT[0..128]: (GA^i)^T row-major, QT[i][m][n] = (GA^i)[n][m]   129*16384
//  g[k][n] = (GA^k GB)[n], k=0..127                              128*128
//  bounds[j][s][n], j=0..64                                      65*3*128
//  cs[s][t][n]  (q,k,v HiPPO states)                             3*8192*128
//  ctx[t][n]                                                     8192*128
//  part[kz][t][n]  (context split-K partials, optional)          16*8192*128

// ---- QT[1] = GA^T ----
__global__ void k_copyT(const float* __restrict__ GA, float* __restrict__ QT1){
  int idx = blockIdx.x*256 + threadIdx.x;   // 0..16383
  int m = idx >> 7, n = idx & 127;
  QT1[idx] = GA[n*N + m];
}

// ---- QT[mlev+i] = QT[mlev] @ QT[i], i=1..mlev (log-doubling of powers) ----
__global__ __launch_bounds__(256) void k_powmm(float* QT, int mlev){
  int i = blockIdx.z + 1;
  const float* Am = QT + (size_t)mlev*(N*N);
  const float* Ai = QT + (size_t)i*(N*N);
  float* C = QT + (size_t)(mlev+i)*(N*N);
  __shared__ __align__(16) float As[16][68];
  __shared__ __align__(16) float Bs[16][68];
  int bm = blockIdx.y, bn = blockIdx.x;
  int tx = threadIdx.x, ty = threadIdx.y;
  int tid = ty*16 + tx;
  float acc[4][4] = {};
  for (int kt = 0; kt < N; kt += 16){
    int row = tid >> 2, kc = (tid & 3) << 2;
    float4 av = *(const float4*)(Am + (size_t)(bm*64+row)*N + kt + kc);
    As[kc+0][row]=av.x; As[kc+1][row]=av.y; As[kc+2][row]=av.z; As[kc+3][row]=av.w;
    int bk = tid >> 4, c0 = (tid & 15) << 2;
    *(float4*)&Bs[bk][c0] = *(const float4*)(Ai + (size_t)(kt+bk)*N + bn*64 + c0);
    __syncthreads();
#pragma unroll
    for (int kk = 0; kk < 16; ++kk){
      float4 a = *(const float4*)&As[kk][ty*4];
      float4 b = *(const float4*)&Bs[kk][tx*4];
      float aa[4]={a.x,a.y,a.z,a.w}, bb[4]={b.x,b.y,b.z,b.w};
#pragma unroll
      for (int ii=0; ii<4; ++ii)
#pragma unroll
        for (int jj=0; jj<4; ++jj) acc[ii][jj] += aa[ii]*bb[jj];
    }
    __syncthreads();
  }
#pragma unroll
  for (int ii=0; ii<4; ++ii){
    float4 vst = make_float4(acc[ii][0],acc[ii][1],acc[ii][2],acc[ii][3]);
    *(float4*)(C + (size_t)(bm*64+ty*4+ii)*N + bn*64 + tx*4) = vst;
  }
}

// ---- g[k] = GA^k GB  (QT stored transposed -> coalesced over n) ----
__global__ void k_g(const float* __restrict__ QT, const float* __restrict__ GB,
                    float* __restrict__ g){
  int kb = blockIdx.x;   // 0..127
  int n = threadIdx.x;   // 128
  if (kb == 0){ g[n] = GB[n]; return; }
  const float* Qk = QT + (size_t)kb*(N*N);
  float acc = 0.0f;
  for (int m = 0; m < N; ++m) acc += Qk[m*N + n]*GB[m];
  g[kb*N + n] = acc;
}

// ---- within-chunk causal conv as triangular-Toeplitz GEMM ----
// cs_local[i][n] = sum_k flp[128+i-k]*g[k][n];   row 127 == locsum (chunk-end local state)
__global__ __launch_bounds__(256) void k_fill_local(const float* __restrict__ fq,
                             const float* __restrict__ fk, const float* __restrict__ fv,
                             const float* __restrict__ g, float* __restrict__ cs){
  int tile = blockIdx.x;          // 0..3 : ti = row-tile, tj = n-tile
  int s = blockIdx.y, j = blockIdx.z;
  const float* f = (s==0)? fq : (s==1)? fk : fv;
  __shared__ float flp[256];
  __shared__ __align__(16) float Bs[16][68];
  int tx = threadIdx.x, ty = threadIdx.y;
  int tid = ty*16 + tx;
  flp[tid] = (tid < 128) ? 0.0f : f[j*L + tid - 128];
  int ti = tile >> 1, tj = tile & 1;
  float acc[4][4] = {};
  int kmax = (ti == 0) ? 64 : 128;   // upper k-tiles are all-zero for the top row-tile
  for (int kt = 0; kt < kmax; kt += 16){
    int bk = tid >> 4, c0 = (tid & 15) << 2;
    *(float4*)&Bs[bk][c0] = *(const float4*)(g + (size_t)(kt+bk)*N + tj*64 + c0);
    __syncthreads();
#pragma unroll
    for (int kk = 0; kk < 16; ++kk){
      float4 b = *(const float4*)&Bs[kk][tx*4];
      int base = 128 + ti*64 + ty*4 - kt - kk;
      float aa[4] = {flp[base], flp[base+1], flp[base+2], flp[base+3]};
      float bb[4] = {b.x, b.y, b.z, b.w};
#pragma unroll
      for (int ii=0; ii<4; ++ii)
#pragma unroll
        for (int jj=0; jj<4; ++jj) acc[ii][jj] += aa[ii]*bb[jj];
    }
    __syncthreads();
  }
#pragma unroll
  for (int ii=0; ii<4; ++ii){
    int row = ti*64 + ty*4 + ii;
    float4 vst = make_float4(acc[ii][0],acc[ii][1],acc[ii][2],acc[ii][3]);
    *(float4*)(cs + ((size_t)s*S + (size_t)j*L + row)*N + tj*64 + tx*4) = vst;
  }
}

// ---- sequential chunk-boundary scan: b_{j+1} = GA^L b_j + loc_j  (loc_j = cs row jL+127) ----
__global__ void k_bscan(const float* __restrict__ QT, const float* __restrict__ cs,
                        float* __restrict__ bounds){
  __shared__ float bc[3][N];
  __shared__ float bnx[3][N];
  int tid = threadIdx.x;          // 384
  int s = tid >> 7, n = tid & 127;
  const float* QL = QT + (size_t)L*(N*N);  // (GA^L)^T
  bc[s][n] = 0.0f;
  bounds[(0*3+s)*N + n] = 0.0f;
  __syncthreads();
  for (int j = 0; j < NC; ++j){
    float acc = cs[((size_t)s*S + (size_t)j*L + 127)*N + n];
    for (int m = 0; m < N; ++m) acc += QL[m*N+n]*bc[s][m];
    bnx[s][n] = acc;
    bounds[((j+1)*3+s)*N + n] = acc;
    __syncthreads();
    bc[s][n] = bnx[s][n];
    __syncthreads();
  }
}

// ---- boundary fill: cs[s][jL+i] += GA^{i+1} b_j ----
__global__ __launch_bounds__(256) void k_fill_bound(const float* __restrict__ QT,
                          const float* __restrict__ bounds, float* __restrict__ cs){
  int i = blockIdx.x;     // 0..L-1
  int jg = blockIdx.y;    // 0..3
  __shared__ float Qs[N*N];   // 64 KB, Qs[m*N+n] = (GA^{i+1})[n][m]
  int tid = threadIdx.x;  // 256
  int p = tid >> 7, n = tid & 127;
  const float* Qg = QT + (size_t)(i+1)*(N*N);
  for (int idx = tid; idx < N*N; idx += 256) Qs[idx] = Qg[idx];
  __syncthreads();
  for (int r = 0; r < 24; ++r){
    int task = jg*48 + p*24 + r;       // 192 (j,s) tasks
    int j = task/3, s = task - 3*j;
    const float* b = bounds + (size_t)task*N;
    float a0=0.f, a1=0.f, a2=0.f, a3=0.f;
    for (int m = 0; m < N; m += 4){
      a0 += Qs[(m+0)*N+n]*b[m+0];
      a1 += Qs[(m+1)*N+n]*b[m+1];
      a2 += Qs[(m+2)*N+n]*b[m+2];
      a3 += Qs[(m+3)*N+n]*b[m+3];
    }
    cs[((size_t)s*S + (size_t)j*L + i)*N + n] += (a0+a1)+(a2+a3);
  }
}

// ---- raw scores: attn[t][u] = 0.25 * qs[t].ks[u]   (A@B^T, 128x128 tiles) ----
__global__ __launch_bounds__(256) void k_score(const float* __restrict__ cs,
                                               float* __restrict__ attn){
  const float* A = cs;                 // q states
  const float* B = cs + (size_t)S*N;   // k states
  __shared__ __align__(16) float As[16][132];
  __shared__ __align__(16) float Bs[16][132];
  int bm = blockIdx.y, bn = blockIdx.x;
  int tx = threadIdx.x, ty = threadIdx.y;
  int tid = ty*16 + tx;
  float acc[8][8] = {};
  for (int kt = 0; kt < N; kt += 16){
#pragma unroll
    for (int ld = 0; ld < 2; ++ld){
      int idx = tid + ld*256;
      int r2 = idx >> 2, k2 = (idx & 3) << 2;
      float4 av = *(const float4*)(A + (size_t)(bm*128+r2)*N + kt + k2);
      As[k2+0][r2]=av.x; As[k2+1][r2]=av.y; As[k2+2][r2]=av.z; As[k2+3][r2]=av.w;
      float4 bv = *(const float4*)(B + (size_t)(bn*128+r2)*N + kt + k2);
      Bs[k2+0][r2]=bv.x; Bs[k2+1][r2]=bv.y; Bs[k2+2][r2]=bv.z; Bs[k2+3][r2]=bv.w;
    }
    __syncthreads();
#pragma unroll
    for (int kk = 0; kk < 16; ++kk){
      float4 a0 = *(const float4*)&As[kk][ty*8];
      float4 a1 = *(const float4*)&As[kk][ty*8+4];
      float4 b0 = *(const float4*)&Bs[kk][tx*4];
      float4 b1 = *(const float4*)&Bs[kk][64+tx*4];
      float aa[8]={a0.x,a0.y,a0.z,a0.w,a1.x,a1.y,a1.z,a1.w};
      float bb[8]={b0.x,b0.y,b0.z,b0.w,b1.x,b1.y,b1.z,b1.w};
#pragma unroll
      for (int ii=0; ii<8; ++ii)
#pragma unroll
        for (int jj=0; jj<8; ++jj) acc[ii][jj] += aa[ii]*bb[jj];
    }
    __syncthreads();
  }
#pragma unroll
  for (int ii=0; ii<8; ++ii){
    size_t r = (size_t)(bm*128 + ty*8 + ii)*S + (size_t)bn*128;
    float4 v0 = make_float4(acc[ii][0]*SCL, acc[ii][1]*SCL, acc[ii][2]*SCL, acc[ii][3]*SCL);
    float4 v1 = make_float4(acc[ii][4]*SCL, acc[ii][5]*SCL, acc[ii][6]*SCL, acc[ii][7]*SCL);
    *(float4*)(attn + r + tx*4)      = v0;
    *(float4*)(attn + r + 64 + tx*4) = v1;
  }
}

// ---- exact row softmax in place (row staged in LDS) ----
__global__ __launch_bounds__(256) void k_softmax(float* __restrict__ attn){
  __shared__ __align__(16) float rowb[S];  // 32 KB
  __shared__ float red[256];
  int t = blockIdx.x;
  int tid = threadIdx.x;
  float4* g4 = (float4*)(attn + (size_t)t*S);
  float4* r4 = (float4*)rowb;
  float mx = -3.0e38f;
  for (int u = tid; u < S/4; u += 256){
    float4 v = g4[u];
    r4[u] = v;
    mx = fmaxf(mx, fmaxf(fmaxf(v.x,v.y), fmaxf(v.z,v.w)));
  }
  red[tid] = mx; __syncthreads();
  for (int st = 128; st > 0; st >>= 1){
    if (tid < st) red[tid] = fmaxf(red[tid], red[tid+st]);
    __syncthreads();
  }
  mx = red[0];
  __syncthreads();
  float sum = 0.0f;
  for (int u = tid; u < S/4; u += 256){
    float4 v = r4[u];
    v.x = __expf(v.x - mx); v.y = __expf(v.y - mx);
    v.z = __expf(v.z - mx); v.w = __expf(v.w - mx);
    r4[u] = v;
    sum += v.x + v.y + v.z + v.w;
  }
  red[tid] = sum; __syncthreads();
  for (int st = 128; st > 0; st >>= 1){
    if (tid < st) red[tid] += red[tid+st];
    __syncthreads();
  }
  float inv = 1.0f / red[0];
  for (int u = tid; u < S/4; u += 256){
    float4 v = r4[u];
    v.x *= inv; v.y *= inv; v.z *= inv; v.w *= inv;
    g4[u] = v;
  }
}

// ---- ctx partials: part[kz] = attn[:, kz-slice] @ vs[kz-slice]   (mode 0: plain store; mode 1: atomicAdd into dst) ----
__global__ __launch_bounds__(256) void k_context(const float* __restrict__ attn,
                       const float* __restrict__ vs, float* __restrict__ dst, int mode){
  __shared__ __align__(16) float As[16][132];
  __shared__ __align__(16) float Bs[16][132];
  int kz = blockIdx.x;   // 0..KSPLIT-1
  int bm = blockIdx.y;   // 0..63
  int tx = threadIdx.x, ty = threadIdx.y;
  int tid = ty*16 + tx;
  const int KC = S / KSPLIT;   // 512
  int k0 = kz*KC;
  float acc[8][8] = {};
  for (int kt = 0; kt < KC; kt += 16){
#pragma unroll
    for (int ld = 0; ld < 2; ++ld){
      int idx = tid + ld*256;
      int r2 = idx >> 2, k2 = (idx & 3) << 2;
      float4 av = *(const float4*)(attn + (size_t)(bm*128+r2)*S + k0 + kt + k2);
      As[k2+0][r2]=av.x; As[k2+1][r2]=av.y; As[k2+2][r2]=av.z; As[k2+3][r2]=av.w;
      int bk = idx >> 5, c0 = (idx & 31) << 2;
      *(float4*)&Bs[bk][c0] = *(const float4*)(vs + (size_t)(k0+kt+bk)*N + c0);
    }
    __syncthreads();
#pragma unroll
    for (int kk = 0; kk < 16; ++kk){
      float4 a0 = *(const float4*)&As[kk][ty*8];
      float4 a1 = *(const float4*)&As[kk][ty*8+4];
      float4 b0 = *(const float4*)&Bs[kk][tx*4];
      float4 b1 = *(const float4*)&Bs[kk][64+tx*4];
      float aa[8]={a0.x,a0.y,a0.z,a0.w,a1.x,a1.y,a1.z,a1.w};
      float bb[8]={b0.x,b0.y,b0.z,b0.w,b1.x,b1.y,b1.z,b1.w};
#pragma unroll
      for (int ii=0; ii<8; ++ii)
#pragma unroll
        for (int jj=0; jj<8; ++jj) acc[ii][jj] += aa[ii]*bb[jj];
    }
    __syncthreads();
  }
  if (mode == 0){
    float* P = dst + (size_t)kz*S*N;
#pragma unroll
    for (int ii=0; ii<8; ++ii){
      int r = bm*128 + ty*8 + ii;
      float4 v0 = make_float4(acc[ii][0],acc[ii][1],acc[ii][2],acc[ii][3]);
      float4 v1 = make_float4(acc[ii][4],acc[ii][5],acc[ii][6],acc[ii][7]);
      *(float4*)(P + (size_t)r*N + tx*4)      = v0;
      *(float4*)(P + (size_t)r*N + 64 + tx*4) = v1;
    }
  } else {
#pragma unroll
    for (int ii=0; ii<8; ++ii){
      int r = bm*128 + ty*8 + ii;
#pragma unroll
      for (int jj=0; jj<4; ++jj){
        atomicAdd(&dst[(size_t)r*N + tx*4 + jj],      acc[ii][jj]);
        atomicAdd(&dst[(size_t)r*N + 64 + tx*4 + jj], acc[ii][4+jj]);
      }
    }
  }
}

// ---- reduce partials -> ctx ----
__global__ __launch_bounds__(256) void k_reduce(const float* __restrict__ part,
                                                float* __restrict__ ctx){
  size_t idx = (size_t)blockIdx.x*256 + threadIdx.x;   // over S*N/4 float4s
  const float4* p4 = (const float4*)part;
  float4 acc = p4[idx];
  const size_t stride = (size_t)S*N/4;
#pragma unroll
  for (int kz = 1; kz < KSPLIT; ++kz){
    float4 v = p4[(size_t)kz*stride + idx];
    acc.x += v.x; acc.y += v.y; acc.z += v.z; acc.w += v.w;
  }
  ((float4*)ctx)[idx] = acc;
}

// ---- out = ctx @ Wp + bp ----
__global__ __launch_bounds__(256) void k_out(const float* __restrict__ ctx,
                   const float* __restrict__ Wp, const float* __restrict__ bp,
                   float* __restrict__ out){
  __shared__ __align__(16) float As[16][68];
  __shared__ __align__(16) float Bs[16][68];
  int bn = blockIdx.x;   // 0..15
  int bm = blockIdx.y;   // 0..127
  int tx = threadIdx.x, ty = threadIdx.y;
  int tid = ty*16 + tx;
  float acc[4][4] = {};
  for (int kt = 0; kt < N; kt += 16){
    int row = tid >> 2, kc = (tid & 3) << 2;
    float4 av = *(const float4*)(ctx + (size_t)(bm*64+row)*N + kt + kc);
    As[kc+0][row]=av.x; As[kc+1][row]=av.y; As[kc+2][row]=av.z; As[kc+3][row]=av.w;
    int bk = tid >> 4, c0 = (tid & 15) << 2;
#pragma unroll
    for (int jj = 0; jj < 4; ++jj){
      int c = bn*64 + c0 + jj;
      Bs[bk][c0+jj] = (c < OD) ? Wp[(size_t)(kt+bk)*OD + c] : 0.0f;
    }
    __syncthreads();
#pragma unroll
    for (int kk = 0; kk < 16; ++kk){
      float4 a = *(const float4*)&As[kk][ty*4];
      float4 b = *(const float4*)&Bs[kk][tx*4];
      float aa[4]={a.x,a.y,a.z,a.w}, bb[4]={b.x,b.y,b.z,b.w};
#pragma unroll
      for (int ii=0; ii<4; ++ii)
#pragma unroll
        for (int jj=0; jj<4; ++jj) acc[ii][jj] += aa[ii]*bb[jj];
    }
    __syncthreads();
  }
#pragma unroll
  for (int ii=0; ii<4; ++ii){
    int r = bm*64 + ty*4 + ii;
#pragma unroll
    for (int jj=0; jj<4; ++jj){
      int c = bn*64 + tx*4 + jj;
      if (c < OD) out[(size_t)r*OD + c] = acc[ii][jj] + bp[c];
    }
  }
}

extern "C" void kernel_launch(void* const* d_in, const int* in_sizes, int n_in,
                              void* d_out, int out_size, void* d_ws, size_t ws_size,
                              hipStream_t stream){
  const float* fq = (const float*)d_in[0];
  const float* fk = (const float*)d_in[1];
  const float* fv = (const float*)d_in[2];
  const float* GA = (const float*)d_in[3];
  const float* GB = (const float*)d_in[4];
  const float* Wp = (const float*)d_in[5];
  const float* bp = (const float*)d_in[6];
  float* out  = (float*)d_out;
  float* attn = out + (size_t)S*OD;

  float* ws     = (float*)d_ws;
  float* QT     = ws;                                // 129*16384
  float* g      = QT + (size_t)129*N*N;              // 128*128
  float* bounds = g + (size_t)L*N;                   // 65*3*128
  float* cs     = bounds + (size_t)(NC+1)*3*N;       // 3*8192*128
  float* ctx    = cs + (size_t)3*S*N;                // 8192*128
  float* part   = ctx + (size_t)S*N;                 // 16*8192*128 (optional)
  size_t need_part = ((size_t)(part - ws) + (size_t)KSPLIT*S*N) * sizeof(float); // ~93 MB
  bool use_part = (ws_size >= need_part);

  k_copyT<<<64, 256, 0, stream>>>(GA, QT + (size_t)N*N);
  for (int m = 1; m < L; m <<= 1)
    k_powmm<<<dim3(2,2,m), dim3(16,16), 0, stream>>>(QT, m);
  k_g<<<128, 128, 0, stream>>>(QT, GB, g);
  k_fill_local<<<dim3(4,3,NC), dim3(16,16), 0, stream>>>(fq, fk, fv, g, cs);
  k_bscan<<<1, 384, 0, stream>>>(QT, cs, bounds);
  k_fill_bound<<<dim3(L,4), 256, 0, stream>>>(QT, bounds, cs);
  k_score<<<dim3(S/128, S/128), dim3(16,16), 0, stream>>>(cs, attn);
  k_softmax<<<S, 256, 0, stream>>>(attn);
  if (use_part){
    k_context<<<dim3(KSPLIT, S/128), dim3(16,16), 0, stream>>>(attn, cs + (size_t)2*S*N, part, 0);
    k_reduce<<<(S*N/4)/256, 256, 0, stream>>>(part, ctx);
  } else {
    hipMemsetAsync(ctx, 0, (size_t)S*N*sizeof(float), stream);
    k_context<<<dim3(KSPLIT, S/128), dim3(16,16), 0, stream>>>(attn, cs + (size_t)2*S*N, ctx, 1);
  }
  k_out<<<dim3(16, S/64), dim3(16,16), 0, stream>>>(ctx, Wp, bp, out);
}